// Round 4
// baseline (109.338 us; speedup 1.0000x reference)
//
#include <hip/hip_runtime.h>
#include <math.h>

#define BB 8
#define HH 256
#define KK 256
#define EE 128
#define HG 4             // h rows per block in kvmn_p
#define HT (HH / HG)     // 64 h-tiles per b

// DPP-based add: x + dpp_mov(x). Template args keep ctrl a compile-time const.
template <int CTRL, int RM>
__device__ __forceinline__ float dpp_add(float x) {
    int d = __builtin_amdgcn_update_dpp(0, __float_as_int(x), CTRL, RM, 0xf, true);
    return x + __int_as_float(d);
}
// Sum over each 32-lane half; valid in lanes 31 and 63.
__device__ __forceinline__ float dpp_reduce_half(float x) {
    x = dpp_add<0x111, 0xf>(x);  // row_shr:1
    x = dpp_add<0x112, 0xf>(x);  // row_shr:2
    x = dpp_add<0x114, 0xf>(x);  // row_shr:4
    x = dpp_add<0x118, 0xf>(x);  // row_shr:8  -> lane15/31/47/63 have row16 sums
    x = dpp_add<0x142, 0xa>(x);  // row_bcast:15 into rows 1,3 -> lanes 31,63 have 32-sums
    return x;
}
// Sum over all 64 lanes; valid in lane 63.
__device__ __forceinline__ float dpp_reduce_wave(float x) {
    x = dpp_reduce_half(x);
    x = dpp_add<0x143, 0xc>(x);  // row_bcast:31 into rows 2,3 -> lane 63 total
    return x;
}

// ---------------- K1: p = exp(u)*mask / rowsum. One block per (b, 4-h tile). ----------------
__global__ __launch_bounds__(256) void kvmn_p(
    const float* __restrict__ hidden,   // [B,H,E]
    const float* __restrict__ key_emb,  // [VOCAB,E]
    const int*   __restrict__ key_seq,  // [B,K]
    const int*   __restrict__ mask,     // [B,H,K]
    float* __restrict__ p_ws)           // [B,H,K]
{
    __shared__ int   sh_ks[KK];
    __shared__ float sh_u[HG][KK];
    __shared__ float sh_part[HG][4];

    const int b    = blockIdx.x >> 6;          // / HT
    const int h0   = (blockIdx.x & (HT - 1)) * HG;
    const int tid  = threadIdx.x;
    const int w    = tid >> 6;
    const int lane = tid & 63;
    const int half = lane >> 5;
    const int sub  = lane & 31;

    sh_ks[tid] = key_seq[b * KK + tid];

    float4 h4[HG];
    #pragma unroll
    for (int j = 0; j < HG; ++j)
        h4[j] = *(const float4*)&hidden[(size_t)(b * HH + h0 + j) * EE + sub * 4];

    __syncthreads();

    const float inv_scale = 0.08838834764831845f; // 1/sqrt(128)

    // phase 1: u[j][k] = dot(hidden[h0+j], key_emb[ks[k]])/sqrt(E); 2 k's per iter
    #pragma unroll 4
    for (int i = 0; i < 32; ++i) {
        const int    k   = w * 64 + i * 2 + half;
        const int    row = sh_ks[k];
        const float4 kv  = *(const float4*)&key_emb[(size_t)row * EE + sub * 4];
        #pragma unroll
        for (int j = 0; j < HG; ++j) {
            float part = kv.x * h4[j].x + kv.y * h4[j].y + kv.z * h4[j].z + kv.w * h4[j].w;
            part = dpp_reduce_half(part);            // VALU, not DS pipe
            if (sub == 31) sh_u[j][k] = part * inv_scale;
        }
    }
    __syncthreads();

    // phase 2: per row j: d = exp(u)*mask; denom over 256 k; p = d/(denom+1e-10)
    float d[HG];
    #pragma unroll
    for (int j = 0; j < HG; ++j) {
        const int m = mask[(size_t)(b * HH + h0 + j) * KK + tid];
        d[j] = expf(sh_u[j][tid]) * (float)m;
        const float s = dpp_reduce_wave(d[j]);
        if (lane == 63) sh_part[j][w] = s;
    }
    __syncthreads();
    #pragma unroll
    for (int j = 0; j < HG; ++j) {
        const float denom = sh_part[j][0] + sh_part[j][1] + sh_part[j][2] + sh_part[j][3];
        p_ws[(size_t)(b * HH + h0 + j) * KK + tid] = d[j] * (1.0f / (denom + 1e-10f));
    }
}

// ---------------- K2: o[b,h,:] = sum_k p[k] * value_emb[vs[k],:]. One block per (b,h). ----------------
__global__ __launch_bounds__(256) void kvmn_o(
    const float* __restrict__ value_emb,  // [FVOCAB,E]
    const int*   __restrict__ value_seq,  // [B,H,K]
    const float* __restrict__ p_ws,       // [B,H,K]
    float* __restrict__ o_ws)             // [B,H,E]
{
    __shared__ float  sh_p[KK];
    __shared__ int    sh_vs[KK];
    __shared__ float4 sh_o4[8][32];

    const int bid  = blockIdx.x;
    const int b    = bid >> 8;
    const int h    = bid & 255;
    const int tid  = threadIdx.x;
    const int w    = tid >> 6;
    const int lane = tid & 63;
    const int half = lane >> 5;
    const int sub  = lane & 31;

    sh_p[tid]  = p_ws[(size_t)(b * HH + h) * KK + tid];
    sh_vs[tid] = value_seq[(size_t)(b * HH + h) * KK + tid];
    __syncthreads();

    float4 acc = make_float4(0.f, 0.f, 0.f, 0.f);
    #pragma unroll 8
    for (int i = 0; i < 32; ++i) {
        const int    k   = w * 64 + i * 2 + half;
        const float  p   = sh_p[k];
        const int    row = sh_vs[k];
        const float4 v   = *(const float4*)&value_emb[(size_t)row * EE + sub * 4];
        acc.x += p * v.x;
        acc.y += p * v.y;
        acc.z += p * v.z;
        acc.w += p * v.w;
    }
    sh_o4[w * 2 + half][sub] = acc;
    __syncthreads();

    if (tid < 32) {
        float4 s = sh_o4[0][tid];
        #pragma unroll
        for (int r = 1; r < 8; ++r) {
            const float4 t = sh_o4[r][tid];
            s.x += t.x; s.y += t.y; s.z += t.z; s.w += t.w;
        }
        *(float4*)&o_ws[(size_t)(b * HH + h) * EE + tid * 4] = s;
    }
}

// ---------------- K3: reduce over H + nonzero-count average. ----------------
__global__ __launch_bounds__(256) void kvmn_reduce(
    const float* __restrict__ o_ws,      // [B,H,E]
    float* __restrict__ out)             // [B,E]
{
    __shared__ float sh_sum[256];
    __shared__ int   sh_cnt[256];

    const int b  = blockIdx.x;
    const int t  = threadIdx.x;
    const int e  = t & 127;
    const int hh = t >> 7;

    float sum = 0.0f;
    int   cnt = 0;
    const float* base = o_ws + (size_t)(b * HH + hh * 128) * EE + e;
    #pragma unroll 8
    for (int h = 0; h < 128; ++h) {
        const float v = base[(size_t)h * EE];
        sum += v;
        cnt += (v != 0.0f) ? 1 : 0;
    }
    sh_sum[t] = sum;
    sh_cnt[t] = cnt;
    __syncthreads();
    if (t < 128) {
        const float s = sh_sum[t] + sh_sum[t + 128];
        const int   c = sh_cnt[t] + sh_cnt[t + 128];
        out[b * EE + t] = s / (float)c;
    }
}

extern "C" void kernel_launch(void* const* d_in, const int* in_sizes, int n_in,
                              void* d_out, int out_size, void* d_ws, size_t ws_size,
                              hipStream_t stream) {
    const float* hidden    = (const float*)d_in[0];
    const float* key_emb   = (const float*)d_in[1];
    const float* value_emb = (const float*)d_in[2];
    const int*   key_seq   = (const int*)d_in[3];
    const int*   value_seq = (const int*)d_in[4];
    const int*   mask      = (const int*)d_in[5];

    float* p_ws = (float*)d_ws;                                    // 2 MB
    float* o_ws = (float*)((char*)d_ws + (size_t)BB * HH * KK * 4); // 1 MB

    kvmn_p<<<BB * HT, 256, 0, stream>>>(hidden, key_emb, key_seq, mask, p_ws);
    kvmn_o<<<BB * HH, 256, 0, stream>>>(value_emb, value_seq, p_ws, o_ws);
    kvmn_reduce<<<BB, 256, 0, stream>>>(o_ws, (float*)d_out);
    (void)in_sizes; (void)n_in; (void)out_size; (void)ws_size;
}

// Round 5
// 102.192 us; speedup vs baseline: 1.0699x; 1.0699x over previous
//
#include <hip/hip_runtime.h>
#include <math.h>

#define BB 8
#define HH 256
#define KK 256
#define EE 128

// DPP-based add: x + dpp_mov(x). Template args keep ctrl a compile-time const.
template <int CTRL, int RM>
__device__ __forceinline__ float dpp_add(float x) {
    int d = __builtin_amdgcn_update_dpp(0, __float_as_int(x), CTRL, RM, 0xf, true);
    return x + __int_as_float(d);
}
// Sum over each 32-lane half; valid in lanes 31 and 63.
__device__ __forceinline__ float dpp_reduce_half(float x) {
    x = dpp_add<0x111, 0xf>(x);  // row_shr:1
    x = dpp_add<0x112, 0xf>(x);  // row_shr:2
    x = dpp_add<0x114, 0xf>(x);  // row_shr:4
    x = dpp_add<0x118, 0xf>(x);  // row_shr:8
    x = dpp_add<0x142, 0xa>(x);  // row_bcast:15 -> lanes 31,63 hold 32-lane sums
    return x;
}
// Sum over all 64 lanes; valid in lane 63.
__device__ __forceinline__ float dpp_reduce_wave(float x) {
    x = dpp_reduce_half(x);
    x = dpp_add<0x143, 0xc>(x);  // row_bcast:31 -> lane 63 holds 64-lane sum
    return x;
}

// ---------------- Kernel A: one block per (b,h), 256 threads = 4 waves. ----------------
// k == tid mapping throughout. Indices and p live in REGISTERS; per-iteration
// row indices / p are broadcast within the 32-lane half via __shfl (no LDS on
// the gather critical path -> iterations fully independent -> deep MLP).
__global__ __launch_bounds__(256) void kvmn_bh(
    const float* __restrict__ hidden,     // [B,H,E]
    const float* __restrict__ key_emb,    // [VOCAB,E]
    const float* __restrict__ value_emb,  // [FVOCAB,E]
    const int*   __restrict__ key_seq,    // [B,K]
    const int*   __restrict__ value_seq,  // [B,H,K]
    const int*   __restrict__ mask,       // [B,H,K]
    float* __restrict__ o_ws)             // [B,H,E]
{
    __shared__ float  sh_u[KK];
    __shared__ float  sh_part[4];
    __shared__ float4 sh_o4[8][32];

    const int bid  = blockIdx.x;
    const int b    = bid >> 8;           // / HH
    const int h    = bid & 255;          // % HH
    const int tid  = threadIdx.x;
    const int w    = tid >> 6;           // wave id 0..3
    const int lane = tid & 63;
    const int half = lane >> 5;          // which 32-lane half
    const int sub  = lane & 31;          // float4 granule within row (e = sub*4)

    // register-staged gather indices (one coalesced load each; k == tid)
    const int ksreg = key_seq[b * KK + tid];
    const int vsreg = value_seq[(size_t)(b * HH + h) * KK + tid];
    const int my_mask = mask[(size_t)(b * HH + h) * KK + tid];

    // per-lane hidden fragment for e = sub*4 .. sub*4+3
    const float4 h4 = *(const float4*)&hidden[(size_t)(b * HH + h) * EE + sub * 4];

    const float inv_scale = 0.08838834764831845f; // 1/sqrt(128)

    // ---- phase 1: u[k] = dot(hidden_row, key_emb[ks[k]])/sqrt(E)
    // (w, half) handles k in [w*64 + half*32, +32); row idx via __shfl broadcast.
    #pragma unroll 16
    for (int i = 0; i < 32; ++i) {
        const int    row = __shfl(ksreg, half * 32 + i, 64);
        const float4 kv  = *(const float4*)&key_emb[(size_t)row * EE + sub * 4];
        float part = kv.x * h4.x + kv.y * h4.y + kv.z * h4.z + kv.w * h4.w;
        part = dpp_reduce_half(part);           // VALU pipe, lanes 31/63 valid
        if (sub == 31) sh_u[w * 64 + half * 32 + i] = part * inv_scale;
    }
    __syncthreads();

    // ---- phase 2: d = exp(u)*mask; denom; p stays in REGISTER pk (lane k==tid)
    const float d = expf(sh_u[tid]) * (float)my_mask;
    float s = dpp_reduce_wave(d);
    if (lane == 63) sh_part[w] = s;
    __syncthreads();
    const float denom = sh_part[0] + sh_part[1] + sh_part[2] + sh_part[3];
    const float pk = d * (1.0f / (denom + 1e-10f));

    // ---- phase 3: o[e] = sum_k p[k]*value_emb[vs[k]][e]; idx+p via __shfl
    float4 acc = make_float4(0.f, 0.f, 0.f, 0.f);
    #pragma unroll 16
    for (int i = 0; i < 32; ++i) {
        const int    src = half * 32 + i;
        const float  p   = __shfl(pk, src, 64);
        const int    row = __shfl(vsreg, src, 64);
        const float4 v   = *(const float4*)&value_emb[(size_t)row * EE + sub * 4];
        acc.x += p * v.x;
        acc.y += p * v.y;
        acc.z += p * v.z;
        acc.w += p * v.w;
    }
    sh_o4[w * 2 + half][sub] = acc;
    __syncthreads();

    // ---- combine 8 partials, plain coalesced store (no atomics)
    if (tid < 32) {
        float4 t = sh_o4[0][tid];
        #pragma unroll
        for (int r = 1; r < 8; ++r) {
            const float4 q = sh_o4[r][tid];
            t.x += q.x; t.y += q.y; t.z += q.z; t.w += q.w;
        }
        *(float4*)&o_ws[(size_t)(b * HH + h) * EE + tid * 4] = t;
    }
}

// ---------------- Kernel B: reduce over H + nonzero-count average. ----------------
__global__ __launch_bounds__(256) void kvmn_reduce(
    const float* __restrict__ o_ws,      // [B,H,E]
    float* __restrict__ out)             // [B,E]
{
    __shared__ float sh_sum[256];
    __shared__ int   sh_cnt[256];

    const int b  = blockIdx.x;
    const int t  = threadIdx.x;
    const int e  = t & 127;
    const int hh = t >> 7;

    float sum = 0.0f;
    int   cnt = 0;
    const float* base = o_ws + (size_t)(b * HH + hh * 128) * EE + e;
    #pragma unroll 8
    for (int h = 0; h < 128; ++h) {
        const float v = base[(size_t)h * EE];
        sum += v;
        cnt += (v != 0.0f) ? 1 : 0;
    }
    sh_sum[t] = sum;
    sh_cnt[t] = cnt;
    __syncthreads();
    if (t < 128) {
        const float s = sh_sum[t] + sh_sum[t + 128];
        const int   c = sh_cnt[t] + sh_cnt[t + 128];
        out[b * EE + t] = s / (float)c;
    }
}

extern "C" void kernel_launch(void* const* d_in, const int* in_sizes, int n_in,
                              void* d_out, int out_size, void* d_ws, size_t ws_size,
                              hipStream_t stream) {
    const float* hidden    = (const float*)d_in[0];
    const float* key_emb   = (const float*)d_in[1];
    const float* value_emb = (const float*)d_in[2];
    const int*   key_seq   = (const int*)d_in[3];
    const int*   value_seq = (const int*)d_in[4];
    const int*   mask      = (const int*)d_in[5];

    float* o_ws = (float*)d_ws;   // 1 MB

    kvmn_bh<<<BB * HH, 256, 0, stream>>>(hidden, key_emb, value_emb,
                                         key_seq, value_seq, mask, o_ws);
    kvmn_reduce<<<BB, 256, 0, stream>>>(o_ws, (float*)d_out);
    (void)in_sizes; (void)n_in; (void)out_size; (void)ws_size;
}